// Round 10
// baseline (310.752 us; speedup 1.0000x reference)
//
#include <hip/hip_runtime.h>

#define N_NODES 100000
#define NPAD    100352          // padded row count (3136*32)
#define DIM     128
#define K2      256             // concatenated K ([preBN/mean | x])
#define SCAN_B  1024
#define NSCANB  ((N_NODES + SCAN_B - 1) / SCAN_B)   // 98
#define CONVB   6250            // convert blocks: N*16/256
#define WBB     16              // wb_build blocks
#define NSHARD  8
#define SHROWS  ((N_NODES + NSHARD - 1) / NSHARD)   // 12500
#define BPS     128             // fill blocks per shard
#define FROWS   32              // rows per fused block (3136 blocks)

typedef __attribute__((ext_vector_type(8))) short bf16x8;
typedef __attribute__((ext_vector_type(4))) float f32x4;

__device__ __forceinline__ void atomAddF(float* p, float v) { unsafeAtomicAdd(p, v); }

__device__ __forceinline__ float bf2f(unsigned short u) {
    union { unsigned u; float f; } c; c.u = ((unsigned)u) << 16; return c.f;
}
__device__ __forceinline__ unsigned short f2bf(float f) {
    union { float f; unsigned u; } c; c.f = f;
    unsigned r = (c.u + 0x7FFF + ((c.u >> 16) & 1)) >> 16;   // RNE
    return (unsigned short)r;
}
__device__ __forceinline__ unsigned packbf(float a, float b) {
    return (unsigned)f2bf(a) | ((unsigned)f2bf(b) << 16);
}
// accumulate 8 packed bf16 (uint4) into f[8]
__device__ __forceinline__ void accum8(float* f, uint4 v) {
    union { unsigned u; float fl; } c;
    c.u = v.x << 16;          f[0] += c.fl;
    c.u = v.x & 0xFFFF0000u;  f[1] += c.fl;
    c.u = v.y << 16;          f[2] += c.fl;
    c.u = v.y & 0xFFFF0000u;  f[3] += c.fl;
    c.u = v.z << 16;          f[4] += c.fl;
    c.u = v.z & 0xFFFF0000u;  f[5] += c.fl;
    c.u = v.w << 16;          f[6] += c.fl;
    c.u = v.w & 0xFFFF0000u;  f[7] += c.fl;
}

// ---------------------------------------------------------------------------
// Phase 1 (merged): hist(dst) | x->bf16 into axk[:,128:256] | W->bf16 frag order
// ---------------------------------------------------------------------------
__global__ __launch_bounds__(256) void phase1_kernel(
    const float* __restrict__ x, const int* __restrict__ ei,
    const float* __restrict__ Wl, const float* __restrict__ Wr,
    unsigned short* __restrict__ axk, unsigned short* __restrict__ wb,
    int* __restrict__ counts, int E, int HB)
{
    int b = blockIdx.x;
    if (b < HB) {                              // ---- histogram of dst
        int e = b * 256 + threadIdx.x;
        if (e < E) atomicAdd(&counts[ei[E + e]], 1);
    } else if (b < HB + CONVB) {               // ---- x -> bf16
        int i = (b - HB) * 256 + threadIdx.x;  // one thread per 8 floats
        int n = i >> 4, c8 = (i & 15) << 3;
        const float4* xp = reinterpret_cast<const float4*>(x + (size_t)n * DIM + c8);
        float4 v0 = xp[0], v1 = xp[1];
        uint4 o;
        o.x = packbf(v0.x, v0.y); o.y = packbf(v0.z, v0.w);
        o.z = packbf(v1.x, v1.y); o.w = packbf(v1.z, v1.w);
        *reinterpret_cast<uint4*>(axk + (size_t)n * K2 + DIM + c8) = o;
    } else {                                   // ---- weights -> fragment order
        int id = (b - HB - CONVB) * 256 + threadIdx.x;   // 4096 total
        int l = id & 63, dt = (id >> 6) & 7, kk = id >> 9;
        int d = dt * 16 + (l & 15);
        int k = kk * 32 + (l >> 4) * 8;
        const float* src = (k < DIM) ? (Wl + (size_t)d * DIM + k)
                                     : (Wr + (size_t)d * DIM + (k - DIM));
        uint4 o;
        o.x = packbf(src[0], src[1]); o.y = packbf(src[2], src[3]);
        o.z = packbf(src[4], src[5]); o.w = packbf(src[6], src[7]);
        *reinterpret_cast<uint4*>(wb + (size_t)id * 8) = o;
    }
}

// ---------------------------------------------------------------------------
// CSR scan
// ---------------------------------------------------------------------------
__global__ __launch_bounds__(SCAN_B) void scan_block_kernel(
    const int* __restrict__ counts, int* __restrict__ incl, int* __restrict__ blksum)
{
    __shared__ int sh[SCAN_B];
    int t = threadIdx.x;
    int i = blockIdx.x * SCAN_B + t;
    sh[t] = (i < N_NODES) ? counts[i] : 0;
    __syncthreads();
    #pragma unroll
    for (int ofs = 1; ofs < SCAN_B; ofs <<= 1) {
        int add = (t >= ofs) ? sh[t - ofs] : 0;
        __syncthreads();
        sh[t] += add;
        __syncthreads();
    }
    if (i < N_NODES) incl[i] = sh[t];
    if (t == SCAN_B - 1) blksum[blockIdx.x] = sh[t];
}

__global__ __launch_bounds__(256) void scan_add_kernel(
    const int* __restrict__ counts, const int* __restrict__ incl,
    const int* __restrict__ blksum,
    int* __restrict__ row_start, int* __restrict__ wo, int E)
{
    __shared__ int soff;
    int b = blockIdx.x;
    if (threadIdx.x == 0) {
        int sb = (b * 256) >> 10;
        int run = 0;
        for (int j = 0; j < sb; ++j) run += blksum[j];
        soff = run;
    }
    __syncthreads();
    int i = b * 256 + threadIdx.x;
    if (i == 0) row_start[N_NODES] = E;
    if (i >= N_NODES) return;
    int excl = incl[i] + soff - counts[i];
    row_start[i] = excl;
    wo[i] = excl;
}

// ---------------------------------------------------------------------------
// XCD-sharded bucket fill (one XCD owns each shard's contiguous srcs window)
// ---------------------------------------------------------------------------
__global__ __launch_bounds__(256) void fill_kernel(
    const int* __restrict__ ei, int* __restrict__ wo, int* __restrict__ srcs, int E)
{
    int shard = blockIdx.x & (NSHARD - 1);
    int widx  = blockIdx.x >> 3;
    int lo = shard * SHROWS;
    int hi = min(lo + SHROWS, N_NODES);
    for (int e = widx * 256 + threadIdx.x; e < E; e += BPS * 256) {
        int dst = ei[E + e];
        int src = ei[e];
        if (dst >= lo && dst < hi) {
            int pos = atomicAdd(&wo[dst], 1);
            srcs[pos] = src;
        }
    }
}

// ---------------------------------------------------------------------------
// Fused aggregate + MFMA GEMM + BN partials.  32 rows/block, 3136 blocks.
// Phase A: 16 groups x 16 lanes, 2 passes; group computes one node's mean
//   (fp32 accum over neighbors' bf16 x-rows) into swizzled Alds, and copies
//   the node's own x-half into swizzled Xlds (coalesced, hides under gather).
// Phase B: 4 waves; wave w: row-tile rt=w&1 (16 rows), d-half dh=w>>1
//   (4 d-tiles). K=256: kk<4 from Alds, kk>=4 from Xlds; B frags from L2.
//   preBN -> bf16 into consumed mean half of axk; per-channel BN partials.
// Swizzle: 16B slot col ^= (row&15)<<3 -> <=2-way banks (free) both ways.
// ---------------------------------------------------------------------------
__global__ __launch_bounds__(256) void fused_agg_gemm_kernel(
    const int* __restrict__ srcs, const int* __restrict__ row_start,
    unsigned short* __restrict__ axk, const unsigned short* __restrict__ wb,
    const float* __restrict__ bl,
    float* __restrict__ ssum, float* __restrict__ ssq)
{
    __shared__ unsigned short Alds[FROWS][DIM];   // 8 KB  (means)
    __shared__ unsigned short Xlds[FROWS][DIM];   // 8 KB  (own x rows)
    __shared__ float sred[4][64];
    __shared__ float qred[4][64];

    const int t = threadIdx.x;
    const int rowbase = blockIdx.x * FROWS;

    // ---------------- Phase A: gather means + stage x ----------------
    {
        const int gid = t >> 4, gl = t & 15;
        const unsigned short* xb = axk + DIM + gl * 8;
        #pragma unroll
        for (int pass = 0; pass < 2; ++pass) {
            int tr = pass * 16 + gid;            // tr & 15 == gid
            int node = rowbase + tr;
            uint4 o  = make_uint4(0u, 0u, 0u, 0u);
            uint4 xo = make_uint4(0u, 0u, 0u, 0u);
            if (node < N_NODES) {
                xo = *reinterpret_cast<const uint4*>(axk + (size_t)node * K2 + DIM + gl * 8);
                int beg = row_start[node], end = row_start[node + 1];
                float f[8] = {0.f, 0.f, 0.f, 0.f, 0.f, 0.f, 0.f, 0.f};
                int e = beg;
                for (; e + 3 < end; e += 4) {    // 4 gathers in flight
                    int s0 = srcs[e], s1 = srcs[e + 1], s2 = srcs[e + 2], s3 = srcs[e + 3];
                    uint4 v0 = *reinterpret_cast<const uint4*>(xb + (size_t)s0 * K2);
                    uint4 v1 = *reinterpret_cast<const uint4*>(xb + (size_t)s1 * K2);
                    uint4 v2 = *reinterpret_cast<const uint4*>(xb + (size_t)s2 * K2);
                    uint4 v3 = *reinterpret_cast<const uint4*>(xb + (size_t)s3 * K2);
                    accum8(f, v0); accum8(f, v1); accum8(f, v2); accum8(f, v3);
                }
                for (; e < end; ++e)
                    accum8(f, *reinterpret_cast<const uint4*>(xb + (size_t)srcs[e] * K2));
                float inv = 1.0f / (float)max(end - beg, 1);
                o.x = packbf(f[0] * inv, f[1] * inv);
                o.y = packbf(f[2] * inv, f[3] * inv);
                o.z = packbf(f[4] * inv, f[5] * inv);
                o.w = packbf(f[6] * inv, f[7] * inv);
            }
            int swz = (gl * 8) ^ (gid << 3);
            *reinterpret_cast<uint4*>(&Alds[tr][swz]) = o;
            *reinterpret_cast<uint4*>(&Xlds[tr][swz]) = xo;
        }
    }
    __syncthreads();

    // ---------------- Phase B: MFMA GEMM ----------------
    const int wave = t >> 6, lane = t & 63;
    const int lrow = lane & 15, lk = lane >> 4;
    const int rt = wave & 1;              // row-tile
    const int dh = wave >> 1;             // d-half

    f32x4 acc[4];
    #pragma unroll
    for (int dt = 0; dt < 4; ++dt) acc[dt] = (f32x4){0.f, 0.f, 0.f, 0.f};

    const bf16x8* __restrict__ bfrag = reinterpret_cast<const bf16x8*>(wb) + lane;
    const int arow = rt * 16 + lrow;

    #pragma unroll
    for (int kk = 0; kk < 8; ++kk) {
        bf16x8 a;
        if (kk < 4)
            a = *reinterpret_cast<const bf16x8*>(
                &Alds[arow][(kk * 32 + lk * 8) ^ (lrow << 3)]);
        else
            a = *reinterpret_cast<const bf16x8*>(
                &Xlds[arow][((kk - 4) * 32 + lk * 8) ^ (lrow << 3)]);
        #pragma unroll
        for (int dt = 0; dt < 4; ++dt) {
            bf16x8 b = bfrag[(kk * 8 + dh * 4 + dt) * 64];   // coalesced, L2-hot
            acc[dt] = __builtin_amdgcn_mfma_f32_16x16x32_bf16(a, b, acc[dt], 0, 0, 0);
        }
    }

    // bias (part of BN input)
    #pragma unroll
    for (int dt = 0; dt < 4; ++dt) {
        float blv = bl[dh * 64 + dt * 16 + lrow];
        #pragma unroll
        for (int r = 0; r < 4; ++r) acc[dt][r] += blv;
    }

    // store pre-BN bf16 into the (consumed) mean half of axk
    #pragma unroll
    for (int r = 0; r < 4; ++r) {
        int row = rowbase + rt * 16 + lk * 4 + r;
        if (row < N_NODES) {
            #pragma unroll
            for (int dt = 0; dt < 4; ++dt)
                axk[(size_t)row * K2 + dh * 64 + dt * 16 + lrow] = f2bf(acc[dt][r]);
        }
    }

    // BN partial stats (fp32, exact)
    #pragma unroll
    for (int dt = 0; dt < 4; ++dt) {
        float s = 0.f, q = 0.f;
        #pragma unroll
        for (int r = 0; r < 4; ++r) {
            int row = rowbase + rt * 16 + lk * 4 + r;
            if (row < N_NODES) { float v = acc[dt][r]; s += v; q = fmaf(v, v, q); }
        }
        s += __shfl_xor(s, 16); q += __shfl_xor(q, 16);
        s += __shfl_xor(s, 32); q += __shfl_xor(q, 32);
        if (lane < 16) { sred[wave][dt * 16 + lane] = s; qred[wave][dt * 16 + lane] = q; }
    }
    __syncthreads();
    if (t < DIM) {
        int h = t >> 6, c = t & 63;           // chans 0..63: waves 0,1; 64..127: waves 2,3
        float s = sred[h * 2][c] + sred[h * 2 + 1][c];
        float q = qred[h * 2][c] + qred[h * 2 + 1][c];
        atomAddF(&ssum[t], s);
        atomAddF(&ssq[t], q);
    }
}

// ---------------------------------------------------------------------------
// Epilogue: BN (stats inlined) + ReLU + residual(bf16 x) -> fp32 out.
// ---------------------------------------------------------------------------
__global__ __launch_bounds__(256) void epilogue_kernel(
    const unsigned short* __restrict__ axk,
    const float* __restrict__ gamma, const float* __restrict__ beta,
    const float* __restrict__ ssum, const float* __restrict__ ssq,
    float* __restrict__ out)
{
    int i = blockIdx.x * 256 + threadIdx.x;   // one thread per 8 channels
    if (i >= N_NODES * 16) return;
    int n = i >> 4, c8 = (i & 15) << 3;
    const float invN = 1.0f / (float)N_NODES;

    ushort4 p0 = *reinterpret_cast<const ushort4*>(axk + (size_t)n * K2 + c8);
    ushort4 p1 = *reinterpret_cast<const ushort4*>(axk + (size_t)n * K2 + c8 + 4);
    ushort4 x0 = *reinterpret_cast<const ushort4*>(axk + (size_t)n * K2 + DIM + c8);
    ushort4 x1 = *reinterpret_cast<const ushort4*>(axk + (size_t)n * K2 + DIM + c8 + 4);

    float o[8];
    unsigned short pv[8] = {p0.x, p0.y, p0.z, p0.w, p1.x, p1.y, p1.z, p1.w};
    unsigned short xv[8] = {x0.x, x0.y, x0.z, x0.w, x1.x, x1.y, x1.z, x1.w};
    #pragma unroll
    for (int j = 0; j < 8; ++j) {
        int d = c8 + j;
        float m = ssum[d] * invN;
        float r = rsqrtf(fmaxf(ssq[d] * invN - m * m, 0.f) + 1e-5f);
        o[j] = fmaxf(gamma[d] * (bf2f(pv[j]) - m) * r + beta[d], 0.f) + bf2f(xv[j]);
    }
    float4 q0 = make_float4(o[0], o[1], o[2], o[3]);
    float4 q1 = make_float4(o[4], o[5], o[6], o[7]);
    *reinterpret_cast<float4*>(out + (size_t)n * DIM + c8) = q0;
    *reinterpret_cast<float4*>(out + (size_t)n * DIM + c8 + 4) = q1;
}

// ---------------------------------------------------------------------------
extern "C" void kernel_launch(void* const* d_in, const int* in_sizes, int n_in,
                              void* d_out, int out_size, void* d_ws, size_t ws_size,
                              hipStream_t stream)
{
    const float* x     = (const float*)d_in[0];
    const int*   ei    = (const int*)  d_in[1];
    const float* Wl    = (const float*)d_in[2];
    const float* bl    = (const float*)d_in[3];
    const float* Wr    = (const float*)d_in[4];
    const float* gamma = (const float*)d_in[5];
    const float* beta  = (const float*)d_in[6];
    float* out = (float*)d_out;

    const int E  = in_sizes[1] / 2;
    const int HB = (E + 255) / 256;

    // ws layout:
    // axk[NPAD*256] bf16 | wb[32768] bf16 | srcs[E] i32 | row_start[N+1] |
    // wo[N] | incl[N] | blksum[128] | counts[N] | ssum[D] | ssq[D]
    char* w = (char*)d_ws;
    unsigned short* axk = (unsigned short*)w;      w += (size_t)NPAD * K2 * 2;
    unsigned short* wb  = (unsigned short*)w;      w += (size_t)32768 * 2;
    int*   srcs      = (int*)w;                    w += (size_t)E * 4;
    int*   row_start = (int*)w;                    w += (size_t)(N_NODES + 1) * 4;
    int*   wo        = (int*)w;                    w += (size_t)N_NODES * 4;
    int*   incl      = (int*)w;                    w += (size_t)N_NODES * 4;
    int*   blksum    = (int*)w;                    w += 128 * 4;
    int*   counts    = (int*)w;                    w += (size_t)N_NODES * 4;
    float* ssum      = (float*)w;                  w += DIM * 4;
    float* ssq       = (float*)w;                  /* end */

    // zero counts + ssum + ssq (contiguous)
    hipMemsetAsync(counts, 0, ((size_t)N_NODES + 2 * DIM) * 4, stream);

    phase1_kernel<<<HB + CONVB + WBB, 256, 0, stream>>>(
        x, ei, Wl, Wr, axk, wb, counts, E, HB);
    scan_block_kernel<<<NSCANB, SCAN_B, 0, stream>>>(counts, incl, blksum);
    scan_add_kernel<<<(N_NODES + 255) / 256, 256, 0, stream>>>(
        counts, incl, blksum, row_start, wo, E);
    fill_kernel<<<NSHARD * BPS, 256, 0, stream>>>(ei, wo, srcs, E);

    fused_agg_gemm_kernel<<<NPAD / FROWS, 256, 0, stream>>>(
        srcs, row_start, axk, wb, bl, ssum, ssq);

    epilogue_kernel<<<(N_NODES * 16 + 255) / 256, 256, 0, stream>>>(
        axk, gamma, beta, ssum, ssq, out);
}